// Round 2
// baseline (614.699 us; speedup 1.0000x reference)
//
#include <hip/hip_runtime.h>
#include <math.h>

// SSIM loss, fused separable implementation, round 2.
// Algebra: s=x+y, d=x-y; 4 separable Gaussian convs (s, d, s^2, d^2) give the
// whole SSIM map:
//   2*mu1mu2 = (mp^2-mm^2)/2 ; mu1^2+mu2^2 = (mp^2+mm^2)/2
//   2*s12    = (varP-varM)/2 ; s11+s22    = (varP+varM)/2
// Structure: block = 512 threads = full 512-col width, 64 output rows/block.
// Vertical pass streams rows with a mod-11 register ring (44 VGPRs); emits
// 8-row chunks into guard-padded, XOR-swizzled LDS; horizontal pass + SSIM
// map + running sum. Raw s_barrier + lgkmcnt-only drain so the next chunk's
// global prefetch (issued before the barrier) stays in flight across it.

#define HH 512
#define WW 512
#define NPLANES 96   // 32*3
#define ROWS 64      // output rows per block
#define CH 8         // chunk rows per barrier period
#define NCHUNK 8
#define LSTRIDE 528  // floats per (row,q): 8 zero-guard + 512 + 8 zero-guard
#define QSTR LSTRIDE
#define RSTR (4 * LSTRIDE)
#define NT 512

#define C1F 0.0001f  // 0.01^2
#define C2F 0.0009f  // 0.03^2

__device__ __forceinline__ int swz(int c) { return c ^ ((c >> 5) & 31); }

extern "C" __global__ __launch_bounds__(NT, 4)
void ssim_main(const float* __restrict__ Ii, const float* __restrict__ Ir,
               const float* __restrict__ win, float* __restrict__ partial) {
  __shared__ float vbuf[CH * RSTR];   // 8*4*528*4B = 67584 B
  __shared__ float psum[8];

  const int tid = threadIdx.x;
  const int b = blockIdx.x;
  const int plane = b >> 3;
  const int r0 = (b & 7) * ROWS;

  // 1-D gaussian from the 2-D window (wave-uniform scalars)
  float g[11];
  {
    float gi = 1.0f / sqrtf(win[5 * 11 + 5]);
#pragma unroll
    for (int j = 0; j < 11; ++j) g[j] = win[55 + j] * gi;
  }

  const size_t pbase = (size_t)plane * (HH * WW) + tid;
  const float* pA = Ii + pbase;   // this thread's column
  const float* pB = Ir + pbase;
  const int wb = 8 + swz(tid);    // swizzled LDS write column

  // zero the guard columns once (512 slots = 1 per thread); never overwritten
  {
    const int lr = tid >> 6, q = (tid >> 4) & 3, p = tid & 15;
    vbuf[lr * RSTR + q * QSTR + (p < 8 ? p : 512 + p)] = 0.f;
  }

  // mod-11 ring accumulators (fully unrolled callers -> static indices)
  float rS[11], rD[11], rP[11], rM[11];
  float pfA[CH], pfB[CH];         // prefetch registers for the next chunk
  float sum = 0.f;

  // branch-free row load (clamped address, select 0 for OOB rows)
  auto loadrow = [&](int u, float& a, float& bb) {
    const int r = r0 - 5 + u;
    const int rc = min(max(r, 0), HH - 1);
    float ta = pA[(size_t)rc * WW];
    float tb = pB[(size_t)rc * WW];
    const bool ok = (unsigned)r < (unsigned)HH;
    a = ok ? ta : 0.f;
    bb = ok ? tb : 0.f;
  };

  // vertical step for input local row u (compile-time); emit local out u-10->lr
  auto vrow = [&](int u, float a, float bb, int lr) {
    const float s = a + bb, d = a - bb;
    const float ss = s * s, dd = d * d;
    {
      const int sl = u % 11;          // init: output local w=u gets tap g[0]
      rS[sl] = g[0] * s; rD[sl] = g[0] * d;
      rP[sl] = g[0] * ss; rM[sl] = g[0] * dd;
    }
#pragma unroll
    for (int t = 1; t < 11; ++t) {
      const int sl = (u + 44 - t) % 11;
      const float w = g[t];
      rS[sl] += w * s; rD[sl] += w * d; rP[sl] += w * ss; rM[sl] += w * dd;
    }
    if (lr >= 0) {                    // output local u-10 complete -> LDS
      const int sl = (u + 1) % 11;    // (u-10) mod 11
      const int base = lr * RSTR + wb;
      vbuf[base           ] = rS[sl];
      vbuf[base +     QSTR] = rD[sl];
      vbuf[base + 2 * QSTR] = rP[sl];
      vbuf[base + 3 * QSTR] = rM[sl];
    }
  };

  // horizontal conv + SSIM for the CH rows in LDS
  auto horiz = [&]() {
    float h0[8], h1[8], h2[8], h3[8];
    const int rb = (tid >> 6) * RSTR;       // wave-uniform row
    const int c0 = (tid & 63) * 8;          // 8 contiguous output cols
#pragma unroll
    for (int j = 0; j < 18; ++j) {
      const int col = c0 + j - 5;
      // interior: swizzled; OOB (<0 or >511): linear into zero guards
      const int ad = rb + 8 + (((unsigned)col > 511u) ? col : swz(col));
      const float v0 = vbuf[ad];
      const float v1 = vbuf[ad + QSTR];
      const float v2 = vbuf[ad + 2 * QSTR];
      const float v3 = vbuf[ad + 3 * QSTR];
      const int clo = (j - 10 > 0) ? (j - 10) : 0;
      const int chi = (j < 7) ? j : 7;
#pragma unroll
      for (int c = clo; c <= chi; ++c) {
        const float w = g[j - c];
        if (c == j) { h0[c] = w * v0; h1[c] = w * v1; h2[c] = w * v2; h3[c] = w * v3; }
        else        { h0[c] += w * v0; h1[c] += w * v1; h2[c] += w * v2; h3[c] += w * v3; }
      }
    }
#pragma unroll
    for (int c = 0; c < 8; ++c) {
      const float mp = h0[c], mm = h1[c];
      const float mp2 = mp * mp, mm2 = mm * mm;
      const float varP = h2[c] - mp2;
      const float varM = h3[c] - mm2;
      const float num1 = 0.5f * (mp2 - mm2) + C1F;
      const float den1 = 0.5f * (mp2 + mm2) + C1F;
      const float num2 = 0.5f * (varP - varM) + C2F;
      const float den2 = 0.5f * (varP + varM) + C2F;
      sum += __fdividef(num1 * num2, den1 * den2);
    }
  };

  // prologue: input rows u=0..9 fill the ring (no emission)
#pragma unroll
  for (int u = 0; u < 10; ++u) {
    float a, bb; loadrow(u, a, bb); vrow(u, a, bb, -1);
  }
  // prefetch chunk 0
#pragma unroll
  for (int i = 0; i < CH; ++i) loadrow(10 + i, pfA[i], pfB[i]);

#pragma unroll
  for (int c = 0; c < NCHUNK; ++c) {
    // vertical: consume prefetched rows, write LDS chunk
#pragma unroll
    for (int i = 0; i < CH; ++i) vrow(10 + 8 * c + i, pfA[i], pfB[i], i);
    // issue next chunk's loads; they stay in flight across both barriers
    if (c + 1 < NCHUNK) {
#pragma unroll
      for (int i = 0; i < CH; ++i) loadrow(18 + 8 * c + i, pfA[i], pfB[i]);
    }
    asm volatile("s_waitcnt lgkmcnt(0)" ::: "memory");  // LDS writes visible
    __builtin_amdgcn_s_barrier();
    horiz();
    asm volatile("s_waitcnt lgkmcnt(0)" ::: "memory");  // LDS reads done
    __builtin_amdgcn_s_barrier();
  }

  // deterministic block reduction
#pragma unroll
  for (int off = 32; off > 0; off >>= 1) sum += __shfl_down(sum, off, 64);
  if ((tid & 63) == 0) psum[tid >> 6] = sum;
  __syncthreads();
  if (tid == 0) {
    float t = 0.f;
#pragma unroll
    for (int wv = 0; wv < 8; ++wv) t += psum[wv];
    partial[b] = t;
  }
}

extern "C" __global__ void ssim_reduce(const float* __restrict__ partial,
                                       float* __restrict__ out, int n, float scale) {
  __shared__ float sm[4];
  const int tid = threadIdx.x;
  float v = 0.f;
  for (int i = tid; i < n; i += 256) v += partial[i];
#pragma unroll
  for (int off = 32; off > 0; off >>= 1) v += __shfl_down(v, off, 64);
  if ((tid & 63) == 0) sm[tid >> 6] = v;
  __syncthreads();
  if (tid == 0) {
    out[0] = 1.0f - (sm[0] + sm[1] + sm[2] + sm[3]) * scale;
  }
}

extern "C" void kernel_launch(void* const* d_in, const int* in_sizes, int n_in,
                              void* d_out, int out_size, void* d_ws, size_t ws_size,
                              hipStream_t stream) {
  const float* Ii = (const float*)d_in[0];
  const float* Ir = (const float*)d_in[1];
  const float* win = (const float*)d_in[2];
  float* out = (float*)d_out;
  float* partial = (float*)d_ws;   // 768 floats

  const int nblocks = NPLANES * 8;  // 768
  ssim_main<<<dim3(nblocks), dim3(NT), 0, stream>>>(Ii, Ir, win, partial);
  ssim_reduce<<<dim3(1), dim3(256), 0, stream>>>(partial, out, nblocks,
                                                 1.0f / 25165824.0f);
}

// Round 3
// 79.708 us; speedup vs baseline: 7.7119x; 7.7119x over previous
//
#include <hip/hip_runtime.h>
#include <math.h>

// SSIM loss, fused separable implementation, round 3.
// Algebra: s=x+y, d=x-y; 4 separable Gaussian convs (s, d, s^2, d^2) give the
// whole SSIM map:
//   2*mu1mu2 = (mp^2-mm^2)/2 ; mu1^2+mu2^2 = (mp^2+mm^2)/2
//   2*s12    = (varP-varM)/2 ; s11+s22    = (varP+varM)/2
// Round-3 changes vs round 2:
//  - __launch_bounds__(512,2): round 2's (512,4) capped VGPR at 64 (HIP treats
//    arg2 as min blocks/CU) -> massive spills (819MB fetch / 1.18GB write of
//    scratch). (512,2) gave 124 VGPR, zero spill, in round 1.
//  - packed fp32: quantities paired as float2 (s,d) and (s^2,d^2);
//    __builtin_elementwise_fma on ext_vector(2) -> v_pk_fma_f32 (VOP3P),
//    halving conv FMA issue count.
//  - LDS holds float4 (S,D,P,M) per (row,col): ds_write_b128 / ds_read_b128,
//    4x fewer LDS issues; XOR swizzle gives optimal 8-lane/bank-quad spread.

#define HH 512
#define WW 512
#define NPLANES 96   // 32*3
#define ROWS 64      // output rows per block
#define CH 8         // chunk rows per barrier period
#define NCHUNK 8
#define LSTRIDE 528  // float4 slots per row: 8 zero-guard + 512 + 8 zero-guard
#define NT 512

#define C1F 0.0001f  // 0.01^2
#define C2F 0.0009f  // 0.03^2

typedef float f32x2 __attribute__((ext_vector_type(2)));

__device__ __forceinline__ int swz(int c) { return c ^ ((c >> 5) & 31); }
__device__ __forceinline__ f32x2 fma2(f32x2 a, f32x2 b, f32x2 c) {
  return __builtin_elementwise_fma(a, b, c);
}

extern "C" __global__ __launch_bounds__(NT, 2)
void ssim_main(const float* __restrict__ Ii, const float* __restrict__ Ir,
               const float* __restrict__ win, float* __restrict__ partial) {
  __shared__ float4 vbuf[CH * LSTRIDE];   // 8*528*16B = 67584 B
  __shared__ float psum[8];

  const int tid = threadIdx.x;
  const int b = blockIdx.x;
  const int plane = b >> 3;
  const int r0 = (b & 7) * ROWS;

  // 1-D gaussian from the 2-D window (wave-uniform scalars)
  float g[11];
  {
    float gi = 1.0f / sqrtf(win[5 * 11 + 5]);
#pragma unroll
    for (int j = 0; j < 11; ++j) g[j] = win[55 + j] * gi;
  }

  const size_t pbase = (size_t)plane * (HH * WW) + tid;
  const float* pA = Ii + pbase;   // this thread's column
  const float* pB = Ir + pbase;
  const int wb = 8 + swz(tid);    // swizzled LDS write column (float4 slot)

  // zero the guard slots once (128 float4 slots); never overwritten
  if (tid < 128) {
    const int lr = tid >> 4, p = tid & 15;
    vbuf[lr * LSTRIDE + (p < 8 ? p : 512 + p)] = make_float4(0.f, 0.f, 0.f, 0.f);
  }

  // mod-11 ring accumulators, packed: r1=(S,D), r2=(P,M). Static indices only.
  f32x2 r1[11], r2[11];
  float pfA[CH], pfB[CH];         // prefetch registers for the next chunk
  float sum = 0.f;

  // branch-free row load (clamped address, select 0 for OOB rows)
  auto loadrow = [&](int u, float& a, float& bb) {
    const int r = r0 - 5 + u;
    const int rc = min(max(r, 0), HH - 1);
    float ta = pA[(size_t)rc * WW];
    float tb = pB[(size_t)rc * WW];
    const bool ok = (unsigned)r < (unsigned)HH;
    a = ok ? ta : 0.f;
    bb = ok ? tb : 0.f;
  };

  // vertical step for input local row u (compile-time); emit local out u-10->lr
  auto vrow = [&](int u, float a, float bb, int lr) {
    f32x2 sd; sd.x = a + bb; sd.y = a - bb;
    const f32x2 pm = sd * sd;
    {
      const int sl = u % 11;          // init: output local w=u gets tap g[0]
      f32x2 w2; w2.x = g[0]; w2.y = g[0];
      r1[sl] = w2 * sd;
      r2[sl] = w2 * pm;
    }
#pragma unroll
    for (int t = 1; t < 11; ++t) {
      const int sl = (u + 44 - t) % 11;
      f32x2 w2; w2.x = g[t]; w2.y = g[t];
      r1[sl] = fma2(w2, sd, r1[sl]);
      r2[sl] = fma2(w2, pm, r2[sl]);
    }
    if (lr >= 0) {                    // output local u-10 complete -> LDS
      const int sl = (u + 1) % 11;    // (u-10) mod 11
      const f32x2 a1 = r1[sl], a2 = r2[sl];
      vbuf[lr * LSTRIDE + wb] = make_float4(a1.x, a1.y, a2.x, a2.y);
    }
  };

  // horizontal conv + SSIM for the CH rows in LDS
  auto horiz = [&]() {
    f32x2 h01[8], h23[8];
    const int rb = (tid >> 6) * LSTRIDE;    // wave-uniform row
    const int c0 = (tid & 63) * 8;          // 8 contiguous output cols
#pragma unroll
    for (int j = 0; j < 18; ++j) {
      const int col = c0 + j - 5;
      // interior: swizzled; OOB (<0 or >511): linear into zero guards
      const int ad = rb + 8 + (((unsigned)col > 511u) ? col : swz(col));
      const float4 v = vbuf[ad];
      f32x2 v01; v01.x = v.x; v01.y = v.y;
      f32x2 v23; v23.x = v.z; v23.y = v.w;
      const int clo = (j - 10 > 0) ? (j - 10) : 0;
      const int chi = (j < 7) ? j : 7;
#pragma unroll
      for (int c = clo; c <= chi; ++c) {
        f32x2 w2; w2.x = g[j - c]; w2.y = g[j - c];
        if (c == j) { h01[c] = w2 * v01;            h23[c] = w2 * v23; }
        else        { h01[c] = fma2(w2, v01, h01[c]); h23[c] = fma2(w2, v23, h23[c]); }
      }
    }
#pragma unroll
    for (int c = 0; c < 8; ++c) {
      const f32x2 m2 = h01[c] * h01[c];     // (mp^2, mm^2)
      const f32x2 var = h23[c] - m2;        // (varP, varM)
      const float num1 = 0.5f * (m2.x - m2.y) + C1F;
      const float den1 = 0.5f * (m2.x + m2.y) + C1F;
      const float num2 = 0.5f * (var.x - var.y) + C2F;
      const float den2 = 0.5f * (var.x + var.y) + C2F;
      sum += __fdividef(num1 * num2, den1 * den2);
    }
  };

  // prologue: input rows u=0..9 fill the ring (no emission)
#pragma unroll
  for (int u = 0; u < 10; ++u) {
    float a, bb; loadrow(u, a, bb); vrow(u, a, bb, -1);
  }
  // prefetch chunk 0
#pragma unroll
  for (int i = 0; i < CH; ++i) loadrow(10 + i, pfA[i], pfB[i]);

#pragma unroll
  for (int c = 0; c < NCHUNK; ++c) {
    // vertical: consume prefetched rows, write LDS chunk
#pragma unroll
    for (int i = 0; i < CH; ++i) vrow(10 + 8 * c + i, pfA[i], pfB[i], i);
    // issue next chunk's loads; they stay in flight across both barriers
    if (c + 1 < NCHUNK) {
#pragma unroll
      for (int i = 0; i < CH; ++i) loadrow(18 + 8 * c + i, pfA[i], pfB[i]);
    }
    asm volatile("s_waitcnt lgkmcnt(0)" ::: "memory");  // LDS writes visible
    __builtin_amdgcn_s_barrier();
    horiz();
    asm volatile("s_waitcnt lgkmcnt(0)" ::: "memory");  // LDS reads done
    __builtin_amdgcn_s_barrier();
  }

  // deterministic block reduction
#pragma unroll
  for (int off = 32; off > 0; off >>= 1) sum += __shfl_down(sum, off, 64);
  if ((tid & 63) == 0) psum[tid >> 6] = sum;
  __syncthreads();
  if (tid == 0) {
    float t = 0.f;
#pragma unroll
    for (int wv = 0; wv < 8; ++wv) t += psum[wv];
    partial[b] = t;
  }
}

extern "C" __global__ void ssim_reduce(const float* __restrict__ partial,
                                       float* __restrict__ out, int n, float scale) {
  __shared__ float sm[4];
  const int tid = threadIdx.x;
  float v = 0.f;
  for (int i = tid; i < n; i += 256) v += partial[i];
#pragma unroll
  for (int off = 32; off > 0; off >>= 1) v += __shfl_down(v, off, 64);
  if ((tid & 63) == 0) sm[tid >> 6] = v;
  __syncthreads();
  if (tid == 0) {
    out[0] = 1.0f - (sm[0] + sm[1] + sm[2] + sm[3]) * scale;
  }
}

extern "C" void kernel_launch(void* const* d_in, const int* in_sizes, int n_in,
                              void* d_out, int out_size, void* d_ws, size_t ws_size,
                              hipStream_t stream) {
  const float* Ii = (const float*)d_in[0];
  const float* Ir = (const float*)d_in[1];
  const float* win = (const float*)d_in[2];
  float* out = (float*)d_out;
  float* partial = (float*)d_ws;   // 768 floats

  const int nblocks = NPLANES * 8;  // 768
  ssim_main<<<dim3(nblocks), dim3(NT), 0, stream>>>(Ii, Ir, win, partial);
  ssim_reduce<<<dim3(1), dim3(256), 0, stream>>>(partial, out, nblocks,
                                                 1.0f / 25165824.0f);
}